// Round 17
// baseline (203.050 us; speedup 1.0000x reference)
//
#include <hip/hip_runtime.h>
#include <cmath>

#define N_NODES 50000
#define N_EDGES 800000
#define D 64
#define N_REL 8

#define NODES_PER_BLK 32
#define TN 16                       // nodes per block in tables_kernel
#define CPAD 4                      // cnt stride in ints (16B/counter)
#define MAXDEG 64                   // ELL row pad; P(deg>64 | Poisson(16)) ~ 1e-20
#define NSEG 8                      // dst segments == XCD count
#define SEG_DIV 6250                // 50000 / 8

// float -> bf16 bits, round-to-nearest-even
static __device__ __forceinline__ unsigned f2bf(float f) {
    unsigned u = __float_as_uint(f);
    return (u + 0x7FFFu + ((u >> 16) & 1u)) >> 16;
}
#define BFLO(u) __uint_as_float((u) << 16)
#define BFHI(u) __uint_as_float((u) & 0xFFFF0000u)

// ---------------------------------------------------------------------------
// K0: w[r*128 + j] = sum_k W_r[r][j][k]  + zero the padded cnt array
// ---------------------------------------------------------------------------
__global__ void wprep_kernel(const float* __restrict__ W_r, float* __restrict__ w,
                             int* __restrict__ cnt) {
    int t = blockIdx.x * blockDim.x + threadIdx.x;
    if (t < N_REL * 2 * D) {
        const float* p = W_r + (size_t)t * D;
        float s = 0.0f;
#pragma unroll
        for (int k = 0; k < D; ++k) s += p[k];
        w[t] = s;
    }
    for (int i = t; i < N_NODES * CPAD; i += gridDim.x * blockDim.x)
        cnt[i] = 0;
}

// ---------------------------------------------------------------------------
// K1: logit tables (tall-skinny GEMM) + xb side-product (packed bf16 x).
// ---------------------------------------------------------------------------
__global__ __launch_bounds__(256) void tables_kernel(
    const float* __restrict__ x, const float* __restrict__ w,
    float* __restrict__ Dn, float* __restrict__ Sr,
    unsigned short* __restrict__ xb)
{
    __shared__ float xs[TN][68];
    __shared__ float ws[16][68];

    int tid = threadIdx.x;
    int n0  = blockIdx.x * TN;

    for (int i = tid; i < 16 * 64; i += 256)
        ws[i >> 6][i & 63] = w[i];
    for (int i = tid; i < TN * 64; i += 256) {
        int n = n0 + (i >> 6);
        xs[i >> 6][i & 63] = (n < N_NODES) ? x[(size_t)n * D + (i & 63)] : 0.f;
    }
    __syncthreads();

    for (int i = tid; i < TN * 64; i += 256) {
        int n = n0 + (i >> 6);
        if (n < N_NODES) xb[(size_t)n0 * D + i] = (unsigned short)f2bf(xs[i >> 6][i & 63]);
    }

    int q = tid & 15, nl = tid >> 4;
    float acc = 0.f;
#pragma unroll
    for (int k = 0; k < 64; k += 4) {
        float4 a = *(const float4*)&xs[nl][k];
        float4 b = *(const float4*)&ws[q][k];
        acc += a.x * b.x + a.y * b.y + a.z * b.z + a.w * b.w;
    }
    int n = n0 + nl;
    if (n < N_NODES) {
        int r = q >> 1;
        if ((q & 1) == 0) Dn[n * 8 + r] = acc;
        else              Sr[n * 8 + r] = acc;
    }
}

// ---------------------------------------------------------------------------
// K2: XCD-partitioned fused ELL scatter (R14 form, plain stores). Streaming
// dst/src/rel loads are NONTEMPORAL so the used-once data doesn't evict
// epack's dirty lines from the XCD L2 (the suspected reason R14's partition
// didn't write-combine: 25.6MB of streaming reads through a 4MB L2).
// ---------------------------------------------------------------------------
__global__ __launch_bounds__(256) void scatter_kernel(
    const int* __restrict__ src, const int* __restrict__ dst,
    const int* __restrict__ rel,
    int* __restrict__ cnt,
    const float* __restrict__ Dn, const float* __restrict__ Sr,
    float2* __restrict__ epack) {
    int seg   = blockIdx.x & (NSEG - 1);
    int chunk = blockIdx.x >> 3;
    int e = chunk * 256 + threadIdx.x;
    if (e >= N_EDGES) return;
    int d = __builtin_nontemporal_load(&dst[e]);
    if ((unsigned)d / SEG_DIV != (unsigned)seg) return;
    int s = __builtin_nontemporal_load(&src[e]);
    int r = __builtin_nontemporal_load(&rel[e]);
    float logit = Dn[d * 8 + r] + Sr[s * 8 + r];
    float gate = 1.0f / (1.0f + __expf(-logit));
    int rank = atomicAdd(&cnt[d * CPAD], 1);
    if (rank < MAXDEG) {
        float2 v; v.x = gate; v.y = __int_as_float(s);
        epack[(size_t)d * MAXDEG + rank] = v;
    }
}

// ---------------------------------------------------------------------------
// K3: aggregation over ELL rows, bf16 gathers, packed bf16 output.
// ---------------------------------------------------------------------------
__global__ __launch_bounds__(256) void agg_kernel(
    const unsigned short* __restrict__ xb,
    const int*   __restrict__ cnt,
    const float2* __restrict__ epack,
    unsigned int* __restrict__ aggb)   // (N_NODES, 32) packed bf16 pairs
{
    int n    = (blockIdx.x * blockDim.x + threadIdx.x) >> 6;
    int lane = threadIdx.x & 63;
    if (n >= N_NODES) return;

    int sub = lane >> 4;      // edge slot 0..3
    int q   = lane & 15;      // dims 4q..4q+3
    int deg = cnt[n * CPAD];
    int m   = (deg < MAXDEG) ? deg : MAXDEG;
    int beg = n * MAXDEG;
    int end = beg + m;

    float ax = 0.f, ay = 0.f, az = 0.f, aw = 0.f;

    for (int base = beg; base < end; base += 8) {
        int e0 = base + sub;
        int e1 = base + 4 + sub;
        float g0 = 0.f, g1 = 0.f;
        int   s0 = 0,   s1 = 0;
        if (e0 < end) { float2 v = epack[e0]; g0 = v.x; s0 = __float_as_int(v.y); }
        if (e1 < end) { float2 v = epack[e1]; g1 = v.x; s1 = __float_as_int(v.y); }
        uint2 u0 = {0u, 0u}, u1 = {0u, 0u};
        if (e0 < end) u0 = *(const uint2*)&xb[(size_t)s0 * D + 4 * q];
        if (e1 < end) u1 = *(const uint2*)&xb[(size_t)s1 * D + 4 * q];
        ax += g0 * BFLO(u0.x) + g1 * BFLO(u1.x);
        ay += g0 * BFHI(u0.x) + g1 * BFHI(u1.x);
        az += g0 * BFLO(u0.y) + g1 * BFLO(u1.y);
        aw += g0 * BFHI(u0.y) + g1 * BFHI(u1.y);
    }

#pragma unroll
    for (int off = 16; off <= 32; off <<= 1) {
        ax += __shfl_xor(ax, off, 64);
        ay += __shfl_xor(ay, off, 64);
        az += __shfl_xor(az, off, 64);
        aw += __shfl_xor(aw, off, 64);
    }

    if (sub == 0) {
        float inv = 1.0f / fmaxf((float)deg, 1.0f);   // normalize by TRUE degree
        uint2 pr;
        pr.x = f2bf(ax * inv) | (f2bf(ay * inv) << 16);
        pr.y = f2bf(az * inv) | (f2bf(aw * inv) << 16);
        *(uint2*)&aggb[(size_t)n * 32 + 2 * q] = pr;
    }
}

// ---------------------------------------------------------------------------
// K4: out = leaky_relu([x, agg] @ W_lin^T + b), all LDS operands bf16-packed.
// ---------------------------------------------------------------------------
__global__ __launch_bounds__(256, 6) void lin_kernel(
    const unsigned int* __restrict__ xbu,   // packed x, 32 uints/node
    const unsigned int* __restrict__ aggb,  // packed agg, 32 uints/node
    const float* __restrict__ W_lin,
    const float* __restrict__ b_lin,
    float* __restrict__ out)
{
    __shared__ unsigned int W2[64][66];
    __shared__ unsigned int c2[NODES_PER_BLK][66];
    __shared__ float b_lds[64];

    int tid = threadIdx.x;
    int n0  = blockIdx.x * NODES_PER_BLK;

    for (int i = tid; i < 64 * 64; i += 256) {
        int j = i >> 6, kp = i & 63;
        float2 wv = *(const float2*)&W_lin[j * 128 + kp * 2];
        W2[j][kp] = f2bf(wv.x) | (f2bf(wv.y) << 16);
    }
    if (tid < 64) b_lds[tid] = b_lin[tid];

    for (int i = tid; i < NODES_PER_BLK * 32; i += 256) {
        int nl = i >> 5, kp = i & 31;
        int n  = n0 + nl;
        unsigned vx = 0u, va = 0u;
        if (n < N_NODES) {
            vx = xbu[(size_t)n * 32 + kp];
            va = aggb[(size_t)n * 32 + kp];
        }
        c2[nl][kp]      = vx;
        c2[nl][32 + kp] = va;
    }
    __syncthreads();

    int tx = tid & 15, ty = tid >> 4;
    float acc[2][4];
#pragma unroll
    for (int i = 0; i < 2; ++i)
#pragma unroll
        for (int jj = 0; jj < 4; ++jj) acc[i][jj] = b_lds[tx + 16 * jj];

#pragma unroll 2
    for (int kp = 0; kp < 64; kp += 2) {      // 2 pairs = 4 dims per iter
        uint2 cu[2], wu[4];
        cu[0] = *(const uint2*)&c2[ty][kp];
        cu[1] = *(const uint2*)&c2[ty + 16][kp];
#pragma unroll
        for (int jj = 0; jj < 4; ++jj)
            wu[jj] = *(const uint2*)&W2[tx + 16 * jj][kp];
#pragma unroll
        for (int i = 0; i < 2; ++i) {
            float cx = BFLO(cu[i].x), cy = BFHI(cu[i].x);
            float cz = BFLO(cu[i].y), cw = BFHI(cu[i].y);
#pragma unroll
            for (int jj = 0; jj < 4; ++jj) {
                acc[i][jj] += cx * BFLO(wu[jj].x) + cy * BFHI(wu[jj].x)
                            + cz * BFLO(wu[jj].y) + cw * BFHI(wu[jj].y);
            }
        }
    }

#pragma unroll
    for (int i = 0; i < 2; ++i) {
        int n = n0 + ty + 16 * i;
        if (n < N_NODES) {
#pragma unroll
            for (int jj = 0; jj < 4; ++jj) {
                float v = acc[i][jj];
                out[(size_t)n * D + tx + 16 * jj] = (v > 0.f) ? v : 0.01f * v;
            }
        }
    }
}

// ---------------------------------------------------------------------------
extern "C" void kernel_launch(void* const* d_in, const int* in_sizes, int n_in,
                              void* d_out, int out_size, void* d_ws, size_t ws_size,
                              hipStream_t stream) {
    const float* x     = (const float*)d_in[0];
    const int*   src   = (const int*)  d_in[1];
    const int*   dst   = (const int*)  d_in[2];
    const int*   rel   = (const int*)  d_in[3];
    const float* W_r   = (const float*)d_in[4];
    const float* W_lin = (const float*)d_in[5];
    const float* b_lin = (const float*)d_in[6];
    float* out = (float*)d_out;

    char* p = (char*)d_ws;
    float*  w       = (float*)p;                p += 4096;
    float*  Dn      = (float*)p;                p += (size_t)N_NODES * 8 * 4;       // 1.6 MB
    float*  Sr      = (float*)p;                p += (size_t)N_NODES * 8 * 4;       // 1.6 MB
    int*    cnt     = (int*)p;                  p += (size_t)N_NODES * CPAD * 4;    // 0.8 MB
    float2* epack   = (float2*)p;               p += (size_t)N_NODES * MAXDEG * 8;  // 25.6 MB
    unsigned short* xb = (unsigned short*)p;    p += (size_t)N_NODES * D * 2;       // 6.4 MB
    unsigned int* aggb = (unsigned int*)p;      p += (size_t)N_NODES * 32 * 4;      // 6.4 MB

    wprep_kernel<<<512, 256, 0, stream>>>(W_r, w, cnt);
    tables_kernel<<<(N_NODES + TN - 1) / TN, 256, 0, stream>>>(x, w, Dn, Sr, xb);
    scatter_kernel<<<NSEG * ((N_EDGES + 255) / 256), 256, 0, stream>>>(
        src, dst, rel, cnt, Dn, Sr, epack);
    agg_kernel<<<(N_NODES * 64 + 255) / 256, 256, 0, stream>>>(xb, cnt, epack, aggb);
    lin_kernel<<<(N_NODES + NODES_PER_BLK - 1) / NODES_PER_BLK, 256, 0, stream>>>(
        (const unsigned int*)xb, aggb, W_lin, b_lin, out);
}

// Round 18
// 199.074 us; speedup vs baseline: 1.0200x; 1.0200x over previous
//
#include <hip/hip_runtime.h>
#include <cmath>

#define N_NODES 50000
#define N_EDGES 800000
#define D 64
#define N_REL 8

#define NODES_PER_BLK 32
#define TN 16                       // nodes per block in tables_kernel
#define CPAD 16                     // cnt stride in ints: 64B line per counter
#define MAXDEG 64                   // ELL row pad; P(deg>64 | Poisson(16)) ~ 1e-20
#define NSEG 8                      // dst segments == XCD count
#define SEG_DIV 6250                // 50000 / 8
#define EPB 1024                    // edges per bin block
#define NBLK_BIN ((N_EDGES + EPB - 1) / EPB)
#define BUCKET_CAP 102400           // per-segment capacity (100K avg + 2.4% slack)
#define SLICES 64                   // blocks per segment in build pass

// float -> bf16 bits, round-to-nearest-even
static __device__ __forceinline__ unsigned f2bf(float f) {
    unsigned u = __float_as_uint(f);
    return (u + 0x7FFFu + ((u >> 16) & 1u)) >> 16;
}
#define BFLO(u) __uint_as_float((u) << 16)
#define BFHI(u) __uint_as_float((u) & 0xFFFF0000u)

// ---------------------------------------------------------------------------
// K0: w rows + zero cnt + zero bucket_cnt
// ---------------------------------------------------------------------------
__global__ void wprep_kernel(const float* __restrict__ W_r, float* __restrict__ w,
                             int* __restrict__ cnt, int* __restrict__ bucket_cnt) {
    int t = blockIdx.x * blockDim.x + threadIdx.x;
    if (t < N_REL * 2 * D) {
        const float* p = W_r + (size_t)t * D;
        float s = 0.0f;
#pragma unroll
        for (int k = 0; k < D; ++k) s += p[k];
        w[t] = s;
    }
    if (t < NSEG) bucket_cnt[t] = 0;
    for (int i = t; i < N_NODES * CPAD; i += gridDim.x * blockDim.x)
        cnt[i] = 0;
}

// ---------------------------------------------------------------------------
// K1: logit tables (tall-skinny GEMM) + xb side-product (packed bf16 x).
// ---------------------------------------------------------------------------
__global__ __launch_bounds__(256) void tables_kernel(
    const float* __restrict__ x, const float* __restrict__ w,
    float* __restrict__ Dn, float* __restrict__ Sr,
    unsigned short* __restrict__ xb)
{
    __shared__ float xs[TN][68];
    __shared__ float ws[16][68];

    int tid = threadIdx.x;
    int n0  = blockIdx.x * TN;

    for (int i = tid; i < 16 * 64; i += 256)
        ws[i >> 6][i & 63] = w[i];
    for (int i = tid; i < TN * 64; i += 256) {
        int n = n0 + (i >> 6);
        xs[i >> 6][i & 63] = (n < N_NODES) ? x[(size_t)n * D + (i & 63)] : 0.f;
    }
    __syncthreads();

    for (int i = tid; i < TN * 64; i += 256) {
        int n = n0 + (i >> 6);
        if (n < N_NODES) xb[(size_t)n0 * D + i] = (unsigned short)f2bf(xs[i >> 6][i & 63]);
    }

    int q = tid & 15, nl = tid >> 4;
    float acc = 0.f;
#pragma unroll
    for (int k = 0; k < 64; k += 4) {
        float4 a = *(const float4*)&xs[nl][k];
        float4 b = *(const float4*)&ws[q][k];
        acc += a.x * b.x + a.y * b.y + a.z * b.z + a.w * b.w;
    }
    int n = n0 + nl;
    if (n < N_NODES) {
        int r = q >> 1;
        if ((q & 1) == 0) Dn[n * 8 + r] = acc;
        else              Sr[n * 8 + r] = acc;
    }
}

// ---------------------------------------------------------------------------
// K2a: bin pass. Each block reads its edge chunk ONCE, computes gates,
// LDS-counting-sorts into 8 dst-segment runs, reserves bucket space (8
// atomics/block), writes coalesced u64 records (gate_f32<<32 | dst<<16 | src;
// src,dst < 65536). Replaces the 8x-redundant streaming reads of R14-R17.
// ---------------------------------------------------------------------------
__global__ __launch_bounds__(256) void bin_kernel(
    const int* __restrict__ src, const int* __restrict__ dst,
    const int* __restrict__ rel,
    const float* __restrict__ Dn, const float* __restrict__ Sr,
    int* __restrict__ bucket_cnt,
    unsigned long long* __restrict__ buckets)
{
    __shared__ unsigned long long buf[EPB];
    __shared__ int hist[NSEG], runoff[NSEG + 1], place[NSEG], gbase[NSEG];

    int tid = threadIdx.x;
    int e0  = blockIdx.x * EPB;

    if (tid < NSEG) hist[tid] = 0;
    __syncthreads();

    unsigned long long rec[4];
    int seg[4];
    int cntl = 0;
#pragma unroll
    for (int j = 0; j < 4; ++j) {
        int e = e0 + tid + j * 256;
        if (e < N_EDGES) {
            int s = src[e], d = dst[e], r = rel[e];
            float logit = Dn[d * 8 + r] + Sr[s * 8 + r];
            float gate = 1.0f / (1.0f + __expf(-logit));
            rec[cntl] = ((unsigned long long)__float_as_uint(gate) << 32)
                      | ((unsigned)d << 16) | (unsigned)s;
            seg[cntl] = d / SEG_DIV;
            atomicAdd(&hist[seg[cntl]], 1);
            ++cntl;
        }
    }
    __syncthreads();

    if (tid == 0) {
        int acc = 0;
        for (int k = 0; k < NSEG; ++k) { runoff[k] = acc; place[k] = acc; acc += hist[k]; }
        runoff[NSEG] = acc;
    }
    __syncthreads();

    for (int j = 0; j < cntl; ++j) {
        int p = atomicAdd(&place[seg[j]], 1);
        buf[p] = rec[j];
    }
    if (tid < NSEG) gbase[tid] = atomicAdd(&bucket_cnt[tid], hist[tid]);
    __syncthreads();

    int total = runoff[NSEG];
    for (int i = tid; i < total; i += 256) {
        int k = 0;
        while (k < NSEG - 1 && i >= runoff[k + 1]) ++k;
        int pos = gbase[k] + (i - runoff[k]);
        if (pos < BUCKET_CAP)
            buckets[(size_t)k * BUCKET_CAP + pos] = buf[i];
    }
}

// ---------------------------------------------------------------------------
// K2b: build pass — per-segment ELL construction, XCD-affine (blockIdx&7 ->
// segment -> XCD under round-robin dispatch). Working set per XCD: bucket
// 800KB (read once) + cnt slice 400KB + touched epack lines ~1.2MB ~= 2.4MB
// < 4MB L2 -> epack dirty lines (~8 stores each) can finally write-combine
// (R14's failure cause: 9.6MB of streaming reads flushed the L2; R17's nt
// loads confirmed partially with WRITE 51->42MB).
// ---------------------------------------------------------------------------
__global__ __launch_bounds__(256) void build_kernel(
    const int* __restrict__ bucket_cnt,
    const unsigned long long* __restrict__ buckets,
    int* __restrict__ cnt,
    float2* __restrict__ epack)
{
    int s     = blockIdx.x & (NSEG - 1);
    int slice = blockIdx.x >> 3;
    int m = bucket_cnt[s];
    if (m > BUCKET_CAP) m = BUCKET_CAP;
    int per = (m + SLICES - 1) / SLICES;
    int b0 = slice * per;
    int b1 = b0 + per; if (b1 > m) b1 = m;
    const unsigned long long* B = buckets + (size_t)s * BUCKET_CAP;

    for (int i = b0 + threadIdx.x; i < b1; i += 256) {
        unsigned long long pk = B[i];
        int sI = (int)(pk & 0xFFFFu);
        int d  = (int)((pk >> 16) & 0xFFFFu);
        float gate = __uint_as_float((unsigned)(pk >> 32));
        int rank = atomicAdd(&cnt[d * CPAD], 1);
        if (rank < MAXDEG) {
            float2 v; v.x = gate; v.y = __int_as_float(sI);
            epack[(size_t)d * MAXDEG + rank] = v;
        }
    }
}

// ---------------------------------------------------------------------------
// K3: aggregation over ELL rows, bf16 gathers, packed bf16 output.
// ---------------------------------------------------------------------------
__global__ __launch_bounds__(256) void agg_kernel(
    const unsigned short* __restrict__ xb,
    const int*   __restrict__ cnt,
    const float2* __restrict__ epack,
    unsigned int* __restrict__ aggb)   // (N_NODES, 32) packed bf16 pairs
{
    int n    = (blockIdx.x * blockDim.x + threadIdx.x) >> 6;
    int lane = threadIdx.x & 63;
    if (n >= N_NODES) return;

    int sub = lane >> 4;      // edge slot 0..3
    int q   = lane & 15;      // dims 4q..4q+3
    int deg = cnt[n * CPAD];
    int m   = (deg < MAXDEG) ? deg : MAXDEG;
    int beg = n * MAXDEG;
    int end = beg + m;

    float ax = 0.f, ay = 0.f, az = 0.f, aw = 0.f;

    for (int base = beg; base < end; base += 8) {
        int e0 = base + sub;
        int e1 = base + 4 + sub;
        float g0 = 0.f, g1 = 0.f;
        int   s0 = 0,   s1 = 0;
        if (e0 < end) { float2 v = epack[e0]; g0 = v.x; s0 = __float_as_int(v.y); }
        if (e1 < end) { float2 v = epack[e1]; g1 = v.x; s1 = __float_as_int(v.y); }
        uint2 u0 = {0u, 0u}, u1 = {0u, 0u};
        if (e0 < end) u0 = *(const uint2*)&xb[(size_t)s0 * D + 4 * q];
        if (e1 < end) u1 = *(const uint2*)&xb[(size_t)s1 * D + 4 * q];
        ax += g0 * BFLO(u0.x) + g1 * BFLO(u1.x);
        ay += g0 * BFHI(u0.x) + g1 * BFHI(u1.x);
        az += g0 * BFLO(u0.y) + g1 * BFLO(u1.y);
        aw += g0 * BFHI(u0.y) + g1 * BFHI(u1.y);
    }

#pragma unroll
    for (int off = 16; off <= 32; off <<= 1) {
        ax += __shfl_xor(ax, off, 64);
        ay += __shfl_xor(ay, off, 64);
        az += __shfl_xor(az, off, 64);
        aw += __shfl_xor(aw, off, 64);
    }

    if (sub == 0) {
        float inv = 1.0f / fmaxf((float)deg, 1.0f);   // normalize by TRUE degree
        uint2 pr;
        pr.x = f2bf(ax * inv) | (f2bf(ay * inv) << 16);
        pr.y = f2bf(az * inv) | (f2bf(aw * inv) << 16);
        *(uint2*)&aggb[(size_t)n * 32 + 2 * q] = pr;
    }
}

// ---------------------------------------------------------------------------
// K4: out = leaky_relu([x, agg] @ W_lin^T + b), all LDS operands bf16-packed.
// ---------------------------------------------------------------------------
__global__ __launch_bounds__(256, 6) void lin_kernel(
    const unsigned int* __restrict__ xbu,   // packed x, 32 uints/node
    const unsigned int* __restrict__ aggb,  // packed agg, 32 uints/node
    const float* __restrict__ W_lin,
    const float* __restrict__ b_lin,
    float* __restrict__ out)
{
    __shared__ unsigned int W2[64][66];
    __shared__ unsigned int c2[NODES_PER_BLK][66];
    __shared__ float b_lds[64];

    int tid = threadIdx.x;
    int n0  = blockIdx.x * NODES_PER_BLK;

    for (int i = tid; i < 64 * 64; i += 256) {
        int j = i >> 6, kp = i & 63;
        float2 wv = *(const float2*)&W_lin[j * 128 + kp * 2];
        W2[j][kp] = f2bf(wv.x) | (f2bf(wv.y) << 16);
    }
    if (tid < 64) b_lds[tid] = b_lin[tid];

    for (int i = tid; i < NODES_PER_BLK * 32; i += 256) {
        int nl = i >> 5, kp = i & 31;
        int n  = n0 + nl;
        unsigned vx = 0u, va = 0u;
        if (n < N_NODES) {
            vx = xbu[(size_t)n * 32 + kp];
            va = aggb[(size_t)n * 32 + kp];
        }
        c2[nl][kp]      = vx;
        c2[nl][32 + kp] = va;
    }
    __syncthreads();

    int tx = tid & 15, ty = tid >> 4;
    float acc[2][4];
#pragma unroll
    for (int i = 0; i < 2; ++i)
#pragma unroll
        for (int jj = 0; jj < 4; ++jj) acc[i][jj] = b_lds[tx + 16 * jj];

#pragma unroll 2
    for (int kp = 0; kp < 64; kp += 2) {      // 2 pairs = 4 dims per iter
        uint2 cu[2], wu[4];
        cu[0] = *(const uint2*)&c2[ty][kp];
        cu[1] = *(const uint2*)&c2[ty + 16][kp];
#pragma unroll
        for (int jj = 0; jj < 4; ++jj)
            wu[jj] = *(const uint2*)&W2[tx + 16 * jj][kp];
#pragma unroll
        for (int i = 0; i < 2; ++i) {
            float cx = BFLO(cu[i].x), cy = BFHI(cu[i].x);
            float cz = BFLO(cu[i].y), cw = BFHI(cu[i].y);
#pragma unroll
            for (int jj = 0; jj < 4; ++jj) {
                acc[i][jj] += cx * BFLO(wu[jj].x) + cy * BFHI(wu[jj].x)
                            + cz * BFLO(wu[jj].y) + cw * BFHI(wu[jj].y);
            }
        }
    }

#pragma unroll
    for (int i = 0; i < 2; ++i) {
        int n = n0 + ty + 16 * i;
        if (n < N_NODES) {
#pragma unroll
            for (int jj = 0; jj < 4; ++jj) {
                float v = acc[i][jj];
                out[(size_t)n * D + tx + 16 * jj] = (v > 0.f) ? v : 0.01f * v;
            }
        }
    }
}

// ---------------------------------------------------------------------------
extern "C" void kernel_launch(void* const* d_in, const int* in_sizes, int n_in,
                              void* d_out, int out_size, void* d_ws, size_t ws_size,
                              hipStream_t stream) {
    const float* x     = (const float*)d_in[0];
    const int*   src   = (const int*)  d_in[1];
    const int*   dst   = (const int*)  d_in[2];
    const int*   rel   = (const int*)  d_in[3];
    const float* W_r   = (const float*)d_in[4];
    const float* W_lin = (const float*)d_in[5];
    const float* b_lin = (const float*)d_in[6];
    float* out = (float*)d_out;

    char* p = (char*)d_ws;
    float*  w        = (float*)p;               p += 4096;
    float*  Dn       = (float*)p;               p += (size_t)N_NODES * 8 * 4;       // 1.6 MB
    float*  Sr       = (float*)p;               p += (size_t)N_NODES * 8 * 4;       // 1.6 MB
    int*    cnt      = (int*)p;                 p += (size_t)N_NODES * CPAD * 4;    // 3.2 MB
    int*    bucket_cnt = (int*)p;               p += 256;
    unsigned long long* buckets = (unsigned long long*)p;
                                                p += (size_t)NSEG * BUCKET_CAP * 8; // 6.55 MB
    float2* epack    = (float2*)p;              p += (size_t)N_NODES * MAXDEG * 8;  // 25.6 MB
    unsigned short* xb = (unsigned short*)p;    p += (size_t)N_NODES * D * 2;       // 6.4 MB
    unsigned int* aggb = (unsigned int*)p;      p += (size_t)N_NODES * 32 * 4;      // 6.4 MB

    wprep_kernel<<<512, 256, 0, stream>>>(W_r, w, cnt, bucket_cnt);
    tables_kernel<<<(N_NODES + TN - 1) / TN, 256, 0, stream>>>(x, w, Dn, Sr, xb);
    bin_kernel<<<NBLK_BIN, 256, 0, stream>>>(src, dst, rel, Dn, Sr, bucket_cnt, buckets);
    build_kernel<<<NSEG * SLICES, 256, 0, stream>>>(bucket_cnt, buckets, cnt, epack);
    agg_kernel<<<(N_NODES * 64 + 255) / 256, 256, 0, stream>>>(xb, cnt, epack, aggb);
    lin_kernel<<<(N_NODES + NODES_PER_BLK - 1) / NODES_PER_BLK, 256, 0, stream>>>(
        (const unsigned int*)xb, aggb, W_lin, b_lin, out);
}

// Round 19
// 184.811 us; speedup vs baseline: 1.0987x; 1.0772x over previous
//
#include <hip/hip_runtime.h>
#include <cmath>

#define N_NODES 50000
#define N_EDGES 800000
#define D 64
#define N_REL 8

#define NODES_PER_BLK 32
#define TN 16                       // nodes per block in tables_kernel
#define CPAD 16                     // cnt stride in ints: 64B line per counter
#define MAXDEG 64                   // ELL row pad; P(deg>64 | Poisson(16)) ~ 1e-20
#define NSEG 8                      // dst segments == XCD count
#define SEG_DIV 6250                // 50000 / 8

// float -> bf16 bits, round-to-nearest-even
static __device__ __forceinline__ unsigned f2bf(float f) {
    unsigned u = __float_as_uint(f);
    return (u + 0x7FFFu + ((u >> 16) & 1u)) >> 16;
}
#define BFLO(u) __uint_as_float((u) << 16)
#define BFHI(u) __uint_as_float((u) & 0xFFFF0000u)

// ---------------------------------------------------------------------------
// K0: w[r*128 + j] = sum_k W_r[r][j][k]  + zero the padded cnt array
// ---------------------------------------------------------------------------
__global__ void wprep_kernel(const float* __restrict__ W_r, float* __restrict__ w,
                             int* __restrict__ cnt) {
    int t = blockIdx.x * blockDim.x + threadIdx.x;
    if (t < N_REL * 2 * D) {
        const float* p = W_r + (size_t)t * D;
        float s = 0.0f;
#pragma unroll
        for (int k = 0; k < D; ++k) s += p[k];
        w[t] = s;
    }
    for (int i = t; i < N_NODES * CPAD; i += gridDim.x * blockDim.x)
        cnt[i] = 0;
}

// ---------------------------------------------------------------------------
// K1: logit tables (tall-skinny GEMM) + xb side-product (packed bf16 x).
// ---------------------------------------------------------------------------
__global__ __launch_bounds__(256) void tables_kernel(
    const float* __restrict__ x, const float* __restrict__ w,
    float* __restrict__ Dn, float* __restrict__ Sr,
    unsigned short* __restrict__ xb)
{
    __shared__ float xs[TN][68];
    __shared__ float ws[16][68];

    int tid = threadIdx.x;
    int n0  = blockIdx.x * TN;

    for (int i = tid; i < 16 * 64; i += 256)
        ws[i >> 6][i & 63] = w[i];
    for (int i = tid; i < TN * 64; i += 256) {
        int n = n0 + (i >> 6);
        xs[i >> 6][i & 63] = (n < N_NODES) ? x[(size_t)n * D + (i & 63)] : 0.f;
    }
    __syncthreads();

    for (int i = tid; i < TN * 64; i += 256) {
        int n = n0 + (i >> 6);
        if (n < N_NODES) xb[(size_t)n0 * D + i] = (unsigned short)f2bf(xs[i >> 6][i & 63]);
    }

    int q = tid & 15, nl = tid >> 4;
    float acc = 0.f;
#pragma unroll
    for (int k = 0; k < 64; k += 4) {
        float4 a = *(const float4*)&xs[nl][k];
        float4 b = *(const float4*)&ws[q][k];
        acc += a.x * b.x + a.y * b.y + a.z * b.z + a.w * b.w;
    }
    int n = n0 + nl;
    if (n < N_NODES) {
        int r = q >> 1;
        if ((q & 1) == 0) Dn[n * 8 + r] = acc;
        else              Sr[n * 8 + r] = acc;
    }
}

// ---------------------------------------------------------------------------
// K2: XCD-partitioned fused ELL scatter (R14 form — best measured: 183us
// total). One atomic+store per edge; 8x blocks, block keeps dst-segment
// (blockIdx&7) for Dn-gather locality. Entry is 4B: gate_bf16<<16 | src_u16
// (src < 2^16). Store count/randomness unchanged (proven irrelevant R6/R16);
// the 4B entry halves agg's sequential epack read.
// ---------------------------------------------------------------------------
__global__ __launch_bounds__(256) void scatter_kernel(
    const int* __restrict__ src, const int* __restrict__ dst,
    const int* __restrict__ rel,
    int* __restrict__ cnt,
    const float* __restrict__ Dn, const float* __restrict__ Sr,
    unsigned int* __restrict__ epack) {
    int seg   = blockIdx.x & (NSEG - 1);
    int chunk = blockIdx.x >> 3;
    int e = chunk * 256 + threadIdx.x;
    if (e >= N_EDGES) return;
    int d = dst[e];
    if ((unsigned)d / SEG_DIV != (unsigned)seg) return;
    int s = src[e], r = rel[e];
    float logit = Dn[d * 8 + r] + Sr[s * 8 + r];
    float gate = 1.0f / (1.0f + __expf(-logit));
    int rank = atomicAdd(&cnt[d * CPAD], 1);
    if (rank < MAXDEG) {
        epack[(size_t)d * MAXDEG + rank] = (f2bf(gate) << 16) | (unsigned)s;
    }
}

// ---------------------------------------------------------------------------
// K3: aggregation over ELL rows, bf16 gathers, packed bf16 output.
// Entry decode: gate = bf16 in high 16 bits, src = low 16 bits.
// ---------------------------------------------------------------------------
__global__ __launch_bounds__(256) void agg_kernel(
    const unsigned short* __restrict__ xb,
    const int*   __restrict__ cnt,
    const unsigned int* __restrict__ epack,
    unsigned int* __restrict__ aggb)   // (N_NODES, 32) packed bf16 pairs
{
    int n    = (blockIdx.x * blockDim.x + threadIdx.x) >> 6;
    int lane = threadIdx.x & 63;
    if (n >= N_NODES) return;

    int sub = lane >> 4;      // edge slot 0..3
    int q   = lane & 15;      // dims 4q..4q+3
    int deg = cnt[n * CPAD];
    int m   = (deg < MAXDEG) ? deg : MAXDEG;
    int beg = n * MAXDEG;
    int end = beg + m;

    float ax = 0.f, ay = 0.f, az = 0.f, aw = 0.f;

    for (int base = beg; base < end; base += 8) {
        int e0 = base + sub;
        int e1 = base + 4 + sub;
        float g0 = 0.f, g1 = 0.f;
        int   s0 = 0,   s1 = 0;
        if (e0 < end) { unsigned pk = epack[e0]; g0 = BFHI(pk); s0 = pk & 0xFFFFu; }
        if (e1 < end) { unsigned pk = epack[e1]; g1 = BFHI(pk); s1 = pk & 0xFFFFu; }
        uint2 u0 = {0u, 0u}, u1 = {0u, 0u};
        if (e0 < end) u0 = *(const uint2*)&xb[(size_t)s0 * D + 4 * q];
        if (e1 < end) u1 = *(const uint2*)&xb[(size_t)s1 * D + 4 * q];
        ax += g0 * BFLO(u0.x) + g1 * BFLO(u1.x);
        ay += g0 * BFHI(u0.x) + g1 * BFHI(u1.x);
        az += g0 * BFLO(u0.y) + g1 * BFLO(u1.y);
        aw += g0 * BFHI(u0.y) + g1 * BFHI(u1.y);
    }

#pragma unroll
    for (int off = 16; off <= 32; off <<= 1) {
        ax += __shfl_xor(ax, off, 64);
        ay += __shfl_xor(ay, off, 64);
        az += __shfl_xor(az, off, 64);
        aw += __shfl_xor(aw, off, 64);
    }

    if (sub == 0) {
        float inv = 1.0f / fmaxf((float)deg, 1.0f);   // normalize by TRUE degree
        uint2 pr;
        pr.x = f2bf(ax * inv) | (f2bf(ay * inv) << 16);
        pr.y = f2bf(az * inv) | (f2bf(aw * inv) << 16);
        *(uint2*)&aggb[(size_t)n * 32 + 2 * q] = pr;
    }
}

// ---------------------------------------------------------------------------
// K4: out = leaky_relu([x, agg] @ W_lin^T + b), all LDS operands bf16-packed.
// ---------------------------------------------------------------------------
__global__ __launch_bounds__(256, 6) void lin_kernel(
    const unsigned int* __restrict__ xbu,   // packed x, 32 uints/node
    const unsigned int* __restrict__ aggb,  // packed agg, 32 uints/node
    const float* __restrict__ W_lin,
    const float* __restrict__ b_lin,
    float* __restrict__ out)
{
    __shared__ unsigned int W2[64][66];
    __shared__ unsigned int c2[NODES_PER_BLK][66];
    __shared__ float b_lds[64];

    int tid = threadIdx.x;
    int n0  = blockIdx.x * NODES_PER_BLK;

    for (int i = tid; i < 64 * 64; i += 256) {
        int j = i >> 6, kp = i & 63;
        float2 wv = *(const float2*)&W_lin[j * 128 + kp * 2];
        W2[j][kp] = f2bf(wv.x) | (f2bf(wv.y) << 16);
    }
    if (tid < 64) b_lds[tid] = b_lin[tid];

    for (int i = tid; i < NODES_PER_BLK * 32; i += 256) {
        int nl = i >> 5, kp = i & 31;
        int n  = n0 + nl;
        unsigned vx = 0u, va = 0u;
        if (n < N_NODES) {
            vx = xbu[(size_t)n * 32 + kp];
            va = aggb[(size_t)n * 32 + kp];
        }
        c2[nl][kp]      = vx;
        c2[nl][32 + kp] = va;
    }
    __syncthreads();

    int tx = tid & 15, ty = tid >> 4;
    float acc[2][4];
#pragma unroll
    for (int i = 0; i < 2; ++i)
#pragma unroll
        for (int jj = 0; jj < 4; ++jj) acc[i][jj] = b_lds[tx + 16 * jj];

#pragma unroll 2
    for (int kp = 0; kp < 64; kp += 2) {      // 2 pairs = 4 dims per iter
        uint2 cu[2], wu[4];
        cu[0] = *(const uint2*)&c2[ty][kp];
        cu[1] = *(const uint2*)&c2[ty + 16][kp];
#pragma unroll
        for (int jj = 0; jj < 4; ++jj)
            wu[jj] = *(const uint2*)&W2[tx + 16 * jj][kp];
#pragma unroll
        for (int i = 0; i < 2; ++i) {
            float cx = BFLO(cu[i].x), cy = BFHI(cu[i].x);
            float cz = BFLO(cu[i].y), cw = BFHI(cu[i].y);
#pragma unroll
            for (int jj = 0; jj < 4; ++jj) {
                acc[i][jj] += cx * BFLO(wu[jj].x) + cy * BFHI(wu[jj].x)
                            + cz * BFLO(wu[jj].y) + cw * BFHI(wu[jj].y);
            }
        }
    }

#pragma unroll
    for (int i = 0; i < 2; ++i) {
        int n = n0 + ty + 16 * i;
        if (n < N_NODES) {
#pragma unroll
            for (int jj = 0; jj < 4; ++jj) {
                float v = acc[i][jj];
                out[(size_t)n * D + tx + 16 * jj] = (v > 0.f) ? v : 0.01f * v;
            }
        }
    }
}

// ---------------------------------------------------------------------------
extern "C" void kernel_launch(void* const* d_in, const int* in_sizes, int n_in,
                              void* d_out, int out_size, void* d_ws, size_t ws_size,
                              hipStream_t stream) {
    const float* x     = (const float*)d_in[0];
    const int*   src   = (const int*)  d_in[1];
    const int*   dst   = (const int*)  d_in[2];
    const int*   rel   = (const int*)  d_in[3];
    const float* W_r   = (const float*)d_in[4];
    const float* W_lin = (const float*)d_in[5];
    const float* b_lin = (const float*)d_in[6];
    float* out = (float*)d_out;

    char* p = (char*)d_ws;
    float*  w       = (float*)p;                p += 4096;
    float*  Dn      = (float*)p;                p += (size_t)N_NODES * 8 * 4;       // 1.6 MB
    float*  Sr      = (float*)p;                p += (size_t)N_NODES * 8 * 4;       // 1.6 MB
    int*    cnt     = (int*)p;                  p += (size_t)N_NODES * CPAD * 4;    // 3.2 MB
    unsigned int* epack = (unsigned int*)p;     p += (size_t)N_NODES * MAXDEG * 4;  // 12.8 MB
    unsigned short* xb = (unsigned short*)p;    p += (size_t)N_NODES * D * 2;       // 6.4 MB
    unsigned int* aggb = (unsigned int*)p;      p += (size_t)N_NODES * 32 * 4;      // 6.4 MB

    wprep_kernel<<<512, 256, 0, stream>>>(W_r, w, cnt);
    tables_kernel<<<(N_NODES + TN - 1) / TN, 256, 0, stream>>>(x, w, Dn, Sr, xb);
    scatter_kernel<<<NSEG * ((N_EDGES + 255) / 256), 256, 0, stream>>>(
        src, dst, rel, cnt, Dn, Sr, epack);
    agg_kernel<<<(N_NODES * 64 + 255) / 256, 256, 0, stream>>>(xb, cnt, epack, aggb);
    lin_kernel<<<(N_NODES + NODES_PER_BLK - 1) / NODES_PER_BLK, 256, 0, stream>>>(
        (const unsigned int*)xb, aggb, W_lin, b_lin, out);
}